// Round 1
// baseline (139.240 us; speedup 1.0000x reference)
//
#include <hip/hip_runtime.h>
#include <math.h>

#define NBINS 128

__global__ void zero_ws_kernel(float* __restrict__ ws) {
    int i = threadIdx.x;
    if (i < NBINS) ws[i] = 0.0f;
}

__global__ __launch_bounds__(256) void hist_kernel(const float* __restrict__ x,
                                                   const float* __restrict__ edges,
                                                   float* __restrict__ ws, int n) {
    __shared__ float sh[NBINS];
    for (int i = threadIdx.x; i < NBINS; i += blockDim.x) sh[i] = 0.0f;
    __syncthreads();

    const float e0 = edges[0];
    const float res = edges[1] - e0;
    const float inv_res = 1.0f / res;
    const float C = 6.0f;                       // ndtr(±6) within 1e-9 of {0,1}
    const float inv_sqrt2 = 0.70710678118654752440f;

    const int stride = gridDim.x * blockDim.x;
    for (int i = blockIdx.x * blockDim.x + threadIdx.x; i < n; i += stride) {
        float xv = x[i * 6];                    // AXIS=0 of row-major (N,6)
        float t = (xv - e0) * inv_res;          // position in bin units; z_j = j - t
        int j0 = (int)ceilf(t - C - 1.0f);
        int j1 = (int)floorf(t + C);
        j0 = max(j0, 0);
        j1 = min(j1, NBINS - 1);
        if (j0 > j1) continue;
        float cprev = 0.5f * (1.0f + erff(((float)j0 - t) * inv_sqrt2));
        for (int j = j0; j <= j1; ++j) {
            float cnext = 0.5f * (1.0f + erff(((float)(j + 1) - t) * inv_sqrt2));
            atomicAdd(&sh[j], cnext - cprev);
            cprev = cnext;
        }
    }
    __syncthreads();
    for (int i = threadIdx.x; i < NBINS; i += blockDim.x) {
        float v = sh[i];
        if (v != 0.0f) atomicAdd(&ws[i], v);
    }
}

__global__ void finalize_kernel(const float* __restrict__ ws,
                                const float* __restrict__ edges,
                                float* __restrict__ out) {
    __shared__ float sh[NBINS];
    int i = threadIdx.x;   // exactly 128 threads
    float v = ws[i];
    sh[i] = v;
    __syncthreads();
    for (int off = NBINS / 2; off >= 1; off >>= 1) {
        if (i < off) sh[i] += sh[i + off];
        __syncthreads();
    }
    float total = sh[0];
    float res = edges[1] - edges[0];
    out[i] = v / (total * res);
}

extern "C" void kernel_launch(void* const* d_in, const int* in_sizes, int n_in,
                              void* d_out, int out_size, void* d_ws, size_t ws_size,
                              hipStream_t stream) {
    const float* x     = (const float*)d_in[0];
    const float* edges = (const float*)d_in[1];
    float* out = (float*)d_out;
    float* ws  = (float*)d_ws;
    int n = in_sizes[0] / 6;

    zero_ws_kernel<<<1, 128, 0, stream>>>(ws);
    hist_kernel<<<1024, 256, 0, stream>>>(x, edges, ws, n);
    finalize_kernel<<<1, 128, 0, stream>>>(ws, edges, out);
}